// Round 10
// baseline (764.036 us; speedup 1.0000x reference)
//
#include <hip/hip_runtime.h>
#include <math.h>

// B=64, T=1000, S=96, A=32, INP=128, H=256. All I/O fp32.
// d_ws: pre fp16 [2][64000][256] = 65,536,000 B | h fp16 same = 65,536,000 B.
// W frag tables (393,216 B) live in the TAIL of the h region (ff reads them
// before rnn overwrites that region). Total ws use = 131,072,000 B.

typedef _Float16 half2_t __attribute__((ext_vector_type(2)));
typedef __attribute__((ext_vector_type(8))) short bf16x8;   // 8 bf16 in 4 VGPRs
typedef __attribute__((ext_vector_type(4))) float f32x4;

__device__ __forceinline__ float fdot2(half2_t a, half2_t b, float c) {
#if __has_builtin(__builtin_amdgcn_fdot2)
    return __builtin_amdgcn_fdot2(a, b, c, false);   // v_dot2_f32_f16
#else
    return c + (float)a[0] * (float)b[0] + (float)a[1] * (float)b[1];
#endif
}

__device__ __forceinline__ short f2bf(float f) {     // fp32 -> bf16 (RNE)
    unsigned u = __builtin_bit_cast(unsigned, f);
    return (short)((u + 0x7FFFu + ((u >> 16) & 1u)) >> 16);
}

// Barrier WITHOUT the vmcnt(0) drain __syncthreads() inserts. Safe when
// inter-wave communication is LDS-only (lgkmcnt covers DS ops).
__device__ __forceinline__ void barrier_lds() {
    __asm__ __volatile__("s_waitcnt lgkmcnt(0)" ::: "memory");
    __builtin_amdgcn_s_barrier();
}

// ---------------------------------------------------------------------------
// Kernel 0: pre-swizzle W into MFMA B-fragment tables (bf16).
// ---------------------------------------------------------------------------
__global__ __launch_bounds__(256, 1)
void prep_kernel(const float* __restrict__ fc11_w, const float* __restrict__ W_ih1,
                 const float* __restrict__ fc21_w, const float* __restrict__ W_ih2,
                 short* __restrict__ tab)
{
    const int e    = blockIdx.x * 256 + threadIdx.x;   // 96*256 = 24576 entries
    const int lane = e & 63;
    const int q = lane >> 4, m = lane & 15;
    const float* W;
    int k0, n;
    if (e < 8192) {                       // G1
        int t_ = e >> 6;
        int ks = t_ & 3, nt = (t_ >> 2) & 15, br = t_ >> 6;
        W = br ? fc21_w : fc11_w;
        k0 = ks * 32 + q * 8; n = nt * 16 + m;
    } else {                              // G2
        int t_ = (e - 8192) >> 6;
        int ks = t_ & 7, nt = (t_ >> 3) & 15, br = t_ >> 7;
        W = br ? W_ih2 : W_ih1;
        k0 = ks * 32 + q * 8; n = nt * 16 + m;
    }
    bf16x8 v;
#pragma unroll
    for (int j = 0; j < 8; ++j) v[j] = f2bf(W[(size_t)(k0 + j) * 256 + n]);
    ((bf16x8*)tab)[e] = v;
}

// ---------------------------------------------------------------------------
// Kernel 1: feed-forward via MFMA. 128-row blocks (grid 1000, 2 m-tiles per
// wave); b-frags loaded once per nt, reused across 2 m-tiles. (unchanged R8/R9)
// ---------------------------------------------------------------------------
__global__ __launch_bounds__(256, 2)
void ff_kernel(const float* __restrict__ state,
               const float* __restrict__ action,
               const float* __restrict__ fc11_b, const float* __restrict__ fc21_b,
               const float* __restrict__ b_hh1, const float* __restrict__ b_ih1,
               const float* __restrict__ b_hh2, const float* __restrict__ b_ih2,
               const short* __restrict__ tab,
               _Float16* __restrict__ pre_out)
{
    __shared__ short X1[128 * 264];       // 67.6 KB bf16, +8 pad per row

    const int tile = blockIdx.x % 500;
    const int br   = blockIdx.x / 500;
    const int tid  = threadIdx.x;
    const int w    = tid >> 6;
    const int lane = tid & 63;
    const int q = lane >> 4, m = lane & 15;
    const int row0 = tile * 128;

    const float* ba = br ? fc21_b : fc11_b;
    const float* bh = br ? b_hh2 : b_hh1;
    const float* bi = br ? b_ih2 : b_ih1;
    const bf16x8* tG1 = (const bf16x8*)tab + (size_t)br * 4096;
    const bf16x8* tG2 = (const bf16x8*)tab + 8192 + (size_t)br * 8192;

    float ba_v[16], bb_v[16];
#pragma unroll
    for (int nt = 0; nt < 16; ++nt) {
        int c = nt * 16 + m;
        ba_v[nt] = ba[c];
        bb_v[nt] = bh[c] + bi[c];
    }

    bf16x8 af[2][4];
#pragma unroll
    for (int mt = 0; mt < 2; ++mt) {
        const int rw = row0 + 64 * mt + 16 * w + m;
#pragma unroll
        for (int ks = 0; ks < 4; ++ks) {
            int k0 = ks * 32 + q * 8;
            const float* src = (k0 < 96) ? (state  + (size_t)rw * 96 + k0)
                                         : (action + (size_t)rw * 32 + (k0 - 96));
            float4 x0 = *(const float4*)src;
            float4 x1 = *(const float4*)(src + 4);
            bf16x8 a;
            a[0] = f2bf(x0.x); a[1] = f2bf(x0.y); a[2] = f2bf(x0.z); a[3] = f2bf(x0.w);
            a[4] = f2bf(x1.x); a[5] = f2bf(x1.y); a[6] = f2bf(x1.z); a[7] = f2bf(x1.w);
            af[mt][ks] = a;
        }
    }

#pragma unroll 4
    for (int nt = 0; nt < 16; ++nt) {
        bf16x8 bf[4];
#pragma unroll
        for (int ks = 0; ks < 4; ++ks) bf[ks] = tG1[(nt * 4 + ks) * 64 + lane];
#pragma unroll
        for (int mt = 0; mt < 2; ++mt) {
            f32x4 acc = {0.f, 0.f, 0.f, 0.f};
#pragma unroll
            for (int ks = 0; ks < 4; ++ks)
                acc = __builtin_amdgcn_mfma_f32_16x16x32_bf16(af[mt][ks], bf[ks], acc, 0, 0, 0);
#pragma unroll
            for (int r = 0; r < 4; ++r) {     // D: col=lane&15, row=q*4+r
                float v = acc[r] + ba_v[nt];
                v = v > 0.f ? v : 0.f;
                X1[(64 * mt + 16 * w + q * 4 + r) * 264 + nt * 16 + m] = f2bf(v);
            }
        }
    }
    // X1 rows for wave w's m-tiles written+read by THIS wave only -> no barrier.

    bf16x8 a2[2][8];
#pragma unroll
    for (int mt = 0; mt < 2; ++mt)
#pragma unroll
        for (int ks = 0; ks < 8; ++ks)
            a2[mt][ks] = *(const bf16x8*)&X1[(64 * mt + 16 * w + m) * 264 + ks * 32 + q * 8];

    _Float16* pre = pre_out + (size_t)br * 64000u * 256u;
#pragma unroll 2
    for (int nt = 0; nt < 16; ++nt) {
        bf16x8 bg[8];
#pragma unroll
        for (int ks = 0; ks < 8; ++ks) bg[ks] = tG2[(nt * 8 + ks) * 64 + lane];
#pragma unroll
        for (int mt = 0; mt < 2; ++mt) {
            f32x4 acc = {0.f, 0.f, 0.f, 0.f};
#pragma unroll
            for (int ks = 0; ks < 8; ++ks)
                acc = __builtin_amdgcn_mfma_f32_16x16x32_bf16(a2[mt][ks], bg[ks], acc, 0, 0, 0);
#pragma unroll
            for (int r = 0; r < 4; ++r) {
                float v = acc[r] + bb_v[nt];
                pre[(size_t)(row0 + 64 * mt + 16 * w + q * 4 + r) * 256 + nt * 16 + m] = (_Float16)v;
            }
        }
    }
}

// ---------------------------------------------------------------------------
// Kernel 2: recurrence, RESTRUCTURED: 8-way K-split, 512 threads/block,
// 128 blocks (one chain each), 2 waves/SIMD.
//  - wave w owns k-slice [32w,32w+32); lane owns cols {4l..4l+3}
//  - weights = 64 half2 VGPRs/thread (fits the 256-reg budget: NO spill,
//    which R6-R9 proved impossible at 128 regs/thread)
//  - 2 waves/SIMD interleave -> exposed latencies halved
//  - h-reads: 4 broadcast b128/wave (32 b128/CU-step, same as 4-way split)
//  - partials: b128 write; lanes 0-31 of wave w reduce cols [32w,32w+32) =
//    exactly the hbuf slice wave w reads next step -> same-wave publish,
//    ONE barrier/step
// ---------------------------------------------------------------------------
__global__ __launch_bounds__(512, 2)
void rnn_kernel(const _Float16* __restrict__ pre_all,
                const float* __restrict__ hn,
                const float* __restrict__ W_hh1,
                const float* __restrict__ W_hh2,
                _Float16* __restrict__ h_out)
{
    __shared__ _Float16 hbuf[256];
    __shared__ float part[2][8][256];   // [parity][kslice][col] = 16 KB

    const int wg = blockIdx.x;          // 0..127 = chain
    const int br = wg >> 6;
    const int b  = wg & 63;
    const float* Whh = br ? W_hh2 : W_hh1;
    const _Float16* pre = pre_all + ((size_t)br * 64000u + (size_t)b * 1000u) * 256u;
    _Float16* hg = h_out + ((size_t)br * 64000u + (size_t)b * 1000u) * 256u;

    const int t    = threadIdx.x;       // 0..511
    const int w    = t >> 6;            // 0..7 = k-slice
    const int lane = t & 63;
    const int k0   = w * 32;
    const int c0   = lane * 4;          // 4 cols per lane (64 lanes x 4 = 256)
    const int cr   = (w << 5) + (lane & 31);   // reduce col of this lane

    // weights: cols {c0..c0+3} x k in [k0,k0+32), half2 along k = 64 VGPRs
    unsigned whb[4][16];
#pragma unroll
    for (int i = 0; i < 16; ++i) {
        float4 lo = *(const float4*)(Whh + (size_t)(k0 + 2 * i) * 256 + c0);
        float4 hi = *(const float4*)(Whh + (size_t)(k0 + 2 * i + 1) * 256 + c0);
        whb[0][i] = __builtin_bit_cast(unsigned, half2_t{(_Float16)lo.x, (_Float16)hi.x});
        whb[1][i] = __builtin_bit_cast(unsigned, half2_t{(_Float16)lo.y, (_Float16)hi.y});
        whb[2][i] = __builtin_bit_cast(unsigned, half2_t{(_Float16)lo.z, (_Float16)hi.z});
        whb[3][i] = __builtin_bit_cast(unsigned, half2_t{(_Float16)lo.w, (_Float16)hi.w});
    }
#pragma unroll
    for (int c = 0; c < 4; ++c)
#pragma unroll
        for (int i = 0; i < 16; ++i)
            __asm__ __volatile__("" : "+v"(whb[c][i]));   // anti-remat pin

    if (t < 256) hbuf[t] = (_Float16)hn[b * 256 + t];
    barrier_lds();

    // 2-deep prefetch of pre[cr] (upper half-wave duplicates lower's value;
    // only lanes<32 consume it in the reduce)
    float pre_c = (float)pre[cr];
    float pre_n = (float)pre[256 + cr];

    for (int tt = 0; tt < 1000; ++tt) {
        const int t2 = (tt + 2 < 1000) ? (tt + 2) : 999;
        const float pre_n2 = (float)pre[(size_t)t2 * 256 + cr];

        // partial dot over own 32-k slice, 4 cols
        const float4* hb = (const float4*)&hbuf[k0];
        float s0 = 0.f, s1 = 0.f, s2 = 0.f, s3 = 0.f;
#pragma unroll
        for (int k = 0; k < 4; ++k) {
            float4 v = hb[k];                       // 8 halves, wave-broadcast
            const half2_t* hh = (const half2_t*)&v;
#define WH(c, idx) __builtin_bit_cast(half2_t, whb[c][idx])
#pragma unroll
            for (int p = 0; p < 4; ++p) {
                s0 = fdot2(hh[p], WH(0, 4 * k + p), s0);
                s1 = fdot2(hh[p], WH(1, 4 * k + p), s1);
                s2 = fdot2(hh[p], WH(2, 4 * k + p), s2);
                s3 = fdot2(hh[p], WH(3, 4 * k + p), s3);
            }
#undef WH
        }
        const int pp = tt & 1;
        *(float4*)&part[pp][w][c0] = float4{s0, s1, s2, s3};  // conflict-free b128
        barrier_lds();                              // publish partials

        // reduce col cr (lanes 0-31 own wave w's next-step hbuf slice)
        if (lane < 32) {
            const float* pc = &part[pp][0][cr];     // stride 256 floats per kslice
            float z = ((pc[0 * 256] + pc[1 * 256]) + (pc[2 * 256] + pc[3 * 256]))
                    + ((pc[4 * 256] + pc[5 * 256]) + (pc[6 * 256] + pc[7 * 256]))
                    + pre_c;
            const float h = 1.0f / (1.0f + __expf(-z));
            const _Float16 h16 = (_Float16)h;
            hbuf[cr] = h16;                         // same-wave consumer slice
            hg[(size_t)tt * 256 + cr] = h16;        // in flight across barrier
        }

        pre_c = pre_n;
        pre_n = pre_n2;
    }
}

// ---------------------------------------------------------------------------
// Kernel 3: q head. q[n] = h[n,:] . qw + qb. One thread per output.
// ---------------------------------------------------------------------------
__global__ __launch_bounds__(256, 2)
void q_kernel(const _Float16* __restrict__ h_all,
              const float* __restrict__ fc12_w, const float* __restrict__ fc12_b,
              const float* __restrict__ fc22_w, const float* __restrict__ fc22_b,
              float* __restrict__ out)
{
    const int n  = blockIdx.x * 256 + threadIdx.x;    // 500 blocks -> n < 128000
    const int br = (n >= 64000);                      // block-uniform
    const float* qwp = br ? fc22_w : fc12_w;
    const float  qb  = br ? fc22_b[0] : fc12_b[0];

    half2_t qw[128];
#pragma unroll
    for (int i = 0; i < 128; ++i)
        qw[i] = half2_t{(_Float16)qwp[2 * i], (_Float16)qwp[2 * i + 1]};

    const float4* hr = (const float4*)(h_all + (size_t)n * 256u);
    float s0 = qb, s1 = 0.f, s2 = 0.f, s3 = 0.f;
#pragma unroll
    for (int k = 0; k < 32; ++k) {
        float4 v = hr[k];
        const half2_t* hh = (const half2_t*)&v;
        s0 = fdot2(hh[0], qw[4 * k + 0], s0);
        s1 = fdot2(hh[1], qw[4 * k + 1], s1);
        s2 = fdot2(hh[2], qw[4 * k + 2], s2);
        s3 = fdot2(hh[3], qw[4 * k + 3], s3);
    }
    out[n] = (s0 + s1) + (s2 + s3);
}

// ---------------------------------------------------------------------------
extern "C" void kernel_launch(void* const* d_in, const int* in_sizes, int n_in,
                              void* d_out, int out_size, void* d_ws, size_t ws_size,
                              hipStream_t stream)
{
    const float* state  = (const float*)d_in[0];
    const float* action = (const float*)d_in[1];
    const float* hn     = (const float*)d_in[2];
    const float* fc11_w = (const float*)d_in[3];
    const float* fc11_b = (const float*)d_in[4];
    const float* W_hh1  = (const float*)d_in[5];
    const float* W_ih1  = (const float*)d_in[6];
    const float* b_hh1  = (const float*)d_in[7];
    const float* b_ih1  = (const float*)d_in[8];
    const float* fc12_w = (const float*)d_in[9];
    const float* fc12_b = (const float*)d_in[10];
    const float* fc21_w = (const float*)d_in[11];
    const float* fc21_b = (const float*)d_in[12];
    const float* W_hh2  = (const float*)d_in[13];
    const float* W_ih2  = (const float*)d_in[14];
    const float* b_hh2  = (const float*)d_in[15];
    const float* b_ih2  = (const float*)d_in[16];
    const float* fc22_w = (const float*)d_in[17];
    const float* fc22_b = (const float*)d_in[18];

    _Float16* pre = (_Float16*)d_ws;                         // 65,536,000 B
    _Float16* hbg = (_Float16*)d_ws + 32768000u;             // 65,536,000 B
    short* tab = (short*)((char*)d_ws + 130678784u);         // frag tables (tail of h region)

    prep_kernel<<<96, 256, 0, stream>>>(fc11_w, W_ih1, fc21_w, W_ih2, tab);
    ff_kernel<<<1000, 256, 0, stream>>>(state, action,
                                        fc11_b, fc21_b, b_hh1, b_ih1,
                                        b_hh2, b_ih2, tab, pre);
    rnn_kernel<<<128, 512, 0, stream>>>(pre, hn, W_hh1, W_hh2, hbg);
    q_kernel<<<500, 256, 0, stream>>>(hbg, fc12_w, fc12_b, fc22_w, fc22_b,
                                      (float*)d_out);
}